// Round 7
// baseline (137.431 us; speedup 1.0000x reference)
//
#include <hip/hip_runtime.h>
#include <hip/hip_bf16.h>

// Problem constants
#define B_  16
#define C_  6
#define T_  512
#define S_  8

#define AS1 __attribute__((address_space(1)))
#define AS3 __attribute__((address_space(3)))

typedef __attribute__((ext_vector_type(8))) short bf16x8;
typedef __attribute__((ext_vector_type(4))) float f32x4;

__device__ __forceinline__ ushort f2bf(float f) {
    __hip_bfloat16 h = __float2bfloat16(f);
    return *reinterpret_cast<ushort*>(&h);
}
__device__ __forceinline__ float bfu2f(ushort u) {
    uint x = (uint)u << 16;
    union { uint u; float f; } c; c.u = x; return c.f;
}

// ---------------------------------------------------------------------------
// Two 512x512 transposes in one launch (Wk->WkT, Wv->WvT)
__global__ void transpose2(const float* __restrict__ s0, const float* __restrict__ s1,
                           float* __restrict__ d0, float* __restrict__ d1) {
    const float* src = blockIdx.z ? s1 : s0;
    float* dst = blockIdx.z ? d1 : d0;
    __shared__ float tile[32][33];
    int bx = blockIdx.x * 32, by = blockIdx.y * 32;
    int tx = threadIdx.x, ty = threadIdx.y;
    for (int i = 0; i < 32; i += 8)
        tile[ty + i][tx] = src[(long)(by + ty + i) * 512 + bx + tx];
    __syncthreads();
    for (int i = 0; i < 32; i += 8)
        dst[(long)(bx + ty + i) * 512 + by + tx] = tile[tx][ty + i];
}

// Two fp32->bf16 512x512 conversions in one launch (Wq, Wo)
__global__ void convert2(const float* __restrict__ s0, const float* __restrict__ s1,
                         ushort* __restrict__ d0, ushort* __restrict__ d1) {
    const float* s = blockIdx.y ? s1 : s0;
    ushort* d = blockIdx.y ? d1 : d0;
    int i = (blockIdx.x * 256 + threadIdx.x) * 4;
    float4 v = *(const float4*)(s + i);
    ushort4 o;
    o.x = f2bf(v.x); o.y = f2bf(v.y); o.z = f2bf(v.z); o.w = f2bf(v.w);
    *(ushort4*)(d + i) = o;
}

// ---------------------------------------------------------------------------
// K/V projections (tiny: 128 rows)
__global__ void kv_proj(const float* __restrict__ key, const float* __restrict__ value,
                        const float* __restrict__ WkT, const float* __restrict__ WvT,
                        const float* __restrict__ bk, const float* __restrict__ bv,
                        float* __restrict__ kout, float* __restrict__ vout) {
    int row = blockIdx.x;      // b*S + s
    int j = threadIdx.x;       // 0..511
    __shared__ float krow[512];
    __shared__ float vrow[512];
    krow[j] = key[(long)row * 512 + j];
    vrow[j] = value[(long)row * 512 + j];
    __syncthreads();
    float ak = bk[j], av = bv[j];
#pragma unroll 8
    for (int f = 0; f < 512; ++f) {
        ak += krow[f] * WkT[(long)f * 512 + j];
        av += vrow[f] * WvT[(long)f * 512 + j];
    }
    kout[(long)row * 512 + j] = ak;
    vout[(long)row * 512 + j] = av;
}

// ---------------------------------------------------------------------------
// MFMA bf16 GEMM. 128x128 tile, BK=64, 4 waves (2x2), 64x64/wave.
// !ABF16 (fp32 A): A reg-staged with PREFETCH DISTANCE 2 (ra[2], kt-loop fully
//   unrolled so all reg indexing is static), W LDS double-buffered via
//   global_load_lds issued at top. Bottom-of-step uses COUNTED vmcnt(8):
//   waits W(kt+1)'s 4 ops only, leaves A(kt+2)'s 8 loads in flight across the
//   barrier. A(kt+1) thus gets a full K-step to land. LDS 48 KB -> 3 blk/CU.
//  ABF16: both operands via global_load_lds, double-buffered, distance 1,
//   single barrier per step (kernel is small; simplicity wins). LDS 64 KB.
// out[m,n] = sum_k A[m,k]*W[n,k] + bias[n]; N=K=512. grid = mpanels*4 (%8==0).
template <int ABF16, int OUTBF>
__global__ __launch_bounds__(256, ABF16 ? 2 : 3)
void gemm_mfma(const void* __restrict__ Ain,
               const ushort* __restrict__ Wbf,
               const float* __restrict__ bias,
               void* __restrict__ out, int mpanels) {
    __shared__ __align__(16) ushort lds[ABF16 ? 32768 : 24576];

    const int bid = blockIdx.x;
    const int cpx = (mpanels * 4) >> 3;
    const int swz = (bid & 7) * cpx + (bid >> 3);   // XCD-bijective (grid%8==0)
    const int bm = (swz >> 2) * 128;
    const int bn = (swz & 3) * 128;

    const int tid  = threadIdx.x;
    const int lane = tid & 63;
    const int wv   = tid >> 6;
    const int wm   = (wv >> 1) * 64;
    const int wn   = (wv & 1) * 64;
    const int ln15 = lane & 15;
    const int ln16 = lane >> 4;

    // fp32-A staging slots: thread -> (rows r0+32i, 8-elem k-chunk kc)
    const int kc = tid & 7;
    const int r0 = tid >> 3;

    float4 ra[2][4][2];   // distance-2 reg staging (indices static after unroll)

    auto LOADA = [&](float4 (&r)[4][2], int k0) {
#pragma unroll
        for (int i = 0; i < 4; ++i) {
            const float* ap = (const float*)Ain + (long)(bm + r0 + 32 * i) * 512 + k0 + kc * 8;
            r[i][0] = *(const float4*)ap;
            r[i][1] = *(const float4*)(ap + 4);
        }
    };
    auto WRITEA = [&](float4 (&r)[4][2], ushort* Adst) {
#pragma unroll
        for (int i = 0; i < 4; ++i) {
            int rr = r0 + 32 * i;
            int idx = rr * 64 + ((kc ^ (rr & 7)) << 3);
            uint4 pk;
            pk.x = (uint)f2bf(r[i][0].x) | ((uint)f2bf(r[i][0].y) << 16);
            pk.y = (uint)f2bf(r[i][0].z) | ((uint)f2bf(r[i][0].w) << 16);
            pk.z = (uint)f2bf(r[i][1].x) | ((uint)f2bf(r[i][1].y) << 16);
            pk.w = (uint)f2bf(r[i][1].z) | ((uint)f2bf(r[i][1].w) << 16);
            *(uint4*)&Adst[idx] = pk;
        }
    };
    // global_load_lds stage of a 128x64 bf16 tile (wave wv -> rows wv*32..+31).
    // Linear LDS dest; source pre-swizzled so swizzled reads see W[row][k0+ch*8].
    auto GLDS = [&](const ushort* gbase, int rowbase, ushort* ldsbase, int k0) {
        int rb = wv * 32 + (lane >> 3);
        int c  = lane & 7;
#pragma unroll
        for (int i = 0; i < 4; ++i) {
            int r = rb + i * 8;
            const ushort* src = gbase + (long)(rowbase + r) * 512 + k0 + ((c ^ (r & 7)) << 3);
            ushort* dst = ldsbase + wv * 2048 + i * 512;   // wave-uniform base
            __builtin_amdgcn_global_load_lds((AS1 const void*)src, (AS3 void*)dst, 16, 0, 0);
        }
    };

    // LDS layout
    ushort* asb0 = lds;                                   // A buf 0
    ushort* asb1 = ABF16 ? (lds + 8192) : lds;            // A buf 1 (ABF16 only)
    ushort* wsb[2] = { ABF16 ? (lds + 16384) : (lds + 8192),
                       ABF16 ? (lds + 24576) : (lds + 16384) };

    f32x4 acc[4][4] = {};

    auto MFMA_PHASE = [&](ushort* Asb, ushort* Wsb) {
        __builtin_amdgcn_s_setprio(1);
#pragma unroll
        for (int kj = 0; kj < 2; ++kj) {
            bf16x8 af[4], bfv[4];
#pragma unroll
            for (int mi = 0; mi < 4; ++mi) {
                int row = wm + mi * 16 + ln15;
                int ch  = kj * 4 + ln16;
                af[mi] = *(const bf16x8*)&Asb[row * 64 + ((ch ^ (row & 7)) << 3)];
            }
#pragma unroll
            for (int ni = 0; ni < 4; ++ni) {
                int row = wn + ni * 16 + ln15;
                int ch  = kj * 4 + ln16;
                bfv[ni] = *(const bf16x8*)&Wsb[row * 64 + ((ch ^ (row & 7)) << 3)];
            }
#pragma unroll
            for (int mi = 0; mi < 4; ++mi)
#pragma unroll
                for (int ni = 0; ni < 4; ++ni)
                    acc[mi][ni] = __builtin_amdgcn_mfma_f32_16x16x32_bf16(
                        af[mi], bfv[ni], acc[mi][ni], 0, 0, 0);
        }
        __builtin_amdgcn_s_setprio(0);
    };

    if (ABF16) {
        // ---- simple distance-1 double-buffered pipeline (small kernel) ----
        GLDS((const ushort*)Ain, bm, asb0, 0);
        GLDS(Wbf, bn, wsb[0], 0);
        asm volatile("s_waitcnt vmcnt(0) lgkmcnt(0)" ::: "memory");
        __builtin_amdgcn_sched_barrier(0);
        __builtin_amdgcn_s_barrier();
        asm volatile("" ::: "memory");
#pragma unroll
        for (int kt = 0; kt < 8; ++kt) {
            ushort* Asb = (kt & 1) ? asb1 : asb0;
            ushort* nAs = (kt & 1) ? asb0 : asb1;
            if (kt < 7) {
                GLDS(Wbf, bn, wsb[(kt + 1) & 1], (kt + 1) * 64);
                GLDS((const ushort*)Ain, bm, nAs, (kt + 1) * 64);
            }
            __builtin_amdgcn_sched_barrier(0);
            MFMA_PHASE(Asb, wsb[kt & 1]);
            asm volatile("s_waitcnt vmcnt(0) lgkmcnt(0)" ::: "memory");
            __builtin_amdgcn_sched_barrier(0);
            __builtin_amdgcn_s_barrier();
            asm volatile("" ::: "memory");
        }
    } else {
        // ---- distance-2 counted pipeline ----
        // prologue: ra[0]<-tile0, W0 staged, ra[1]<-tile1 (stays in flight)
        LOADA(ra[0], 0);
        GLDS(Wbf, bn, wsb[0], 0);
        LOADA(ra[1], 64);
        WRITEA(ra[0], asb0);                       // compiler waits ra[0] only
        asm volatile("s_waitcnt vmcnt(8) lgkmcnt(0)" ::: "memory");  // W0 done; ra[1] flies
        __builtin_amdgcn_sched_barrier(0);
        __builtin_amdgcn_s_barrier();
        asm volatile("" ::: "memory");

#pragma unroll
        for (int kt = 0; kt < 8; ++kt) {
            // top: stage W(kt+1) -> other W buf; A(kt+2) -> ra[kt&1] (now free)
            if (kt < 7) GLDS(Wbf, bn, wsb[(kt + 1) & 1], (kt + 1) * 64);
            if (kt + 2 < 8) LOADA(ra[kt & 1], (kt + 2) * 64);
            __builtin_amdgcn_sched_barrier(0);

            MFMA_PHASE(asb0, wsb[kt & 1]);

            // bar1: all waves done reading asb0
            asm volatile("" ::: "memory");
            __builtin_amdgcn_s_barrier();
            asm volatile("" ::: "memory");

            if (kt < 7) WRITEA(ra[(kt + 1) & 1], asb0);   // tile kt+1 (loaded @ kt-1)

            // counted wait: drain W(kt+1) (4 ops), keep A(kt+2) (8 ops) in flight
            if (kt < 6) {
                asm volatile("s_waitcnt vmcnt(8) lgkmcnt(0)" ::: "memory");
            } else {
                asm volatile("s_waitcnt vmcnt(0) lgkmcnt(0)" ::: "memory");
            }
            __builtin_amdgcn_sched_barrier(0);
            __builtin_amdgcn_s_barrier();
            asm volatile("" ::: "memory");
        }
    }

    // ---- epilogue ----
    float bsv[4];
#pragma unroll
    for (int ni = 0; ni < 4; ++ni)
        bsv[ni] = bias[bn + wn + ni * 16 + ln15];

    if (OUTBF) {
        ushort* eb = lds;    // 128x128 bf16 = 32 KB
#pragma unroll
        for (int mi = 0; mi < 4; ++mi)
#pragma unroll
            for (int j = 0; j < 4; ++j) {
                int row = wm + mi * 16 + ln16 * 4 + j;
#pragma unroll
                for (int ni = 0; ni < 4; ++ni) {
                    int col = wn + ni * 16 + ln15;
                    int cs  = col ^ ((row & 12) << 2);
                    eb[row * 128 + cs] = f2bf(acc[mi][ni][j] + bsv[ni]);
                }
            }
        asm volatile("s_waitcnt lgkmcnt(0)" ::: "memory");
        __builtin_amdgcn_sched_barrier(0);
        __builtin_amdgcn_s_barrier();
        asm volatile("" ::: "memory");
#pragma unroll
        for (int i = 0; i < 8; ++i) {
            int idx = i * 2048 + tid * 8;
            int row = idx >> 7, col = idx & 127;
            int cs  = col ^ ((row & 12) << 2);
            uint4 v = *(const uint4*)&eb[row * 128 + cs];
            *(uint4*)((ushort*)out + (long)(bm + row) * 512 + bn + col) = v;
        }
    } else {
        // fp32 out: stage in two 64-row halves (32 KB each)
        float* ef = (float*)lds;
#pragma unroll
        for (int half = 0; half < 2; ++half) {
            if (wm == half * 64) {
#pragma unroll
                for (int mi = 0; mi < 4; ++mi)
#pragma unroll
                    for (int j = 0; j < 4; ++j) {
                        int lr = mi * 16 + ln16 * 4 + j;
#pragma unroll
                        for (int ni = 0; ni < 4; ++ni) {
                            int col = wn + ni * 16 + ln15;
                            int cs  = col ^ ((lr & 12) << 2);
                            ef[lr * 128 + cs] = acc[mi][ni][j] + bsv[ni];
                        }
                    }
            }
            asm volatile("s_waitcnt lgkmcnt(0)" ::: "memory");
            __builtin_amdgcn_sched_barrier(0);
            __builtin_amdgcn_s_barrier();
            asm volatile("" ::: "memory");
#pragma unroll
            for (int i = 0; i < 8; ++i) {
                int idx = i * 1024 + tid * 4;
                int lr = idx >> 7, col = idx & 127;
                int cs = col ^ ((lr & 12) << 2);
                float4 v = *(const float4*)&ef[lr * 128 + cs];
                *(float4*)((float*)out + (long)(bm + half * 64 + lr) * 512 + bn + col) = v;
            }
            if (half == 0) {
                asm volatile("" ::: "memory");
                __builtin_amdgcn_s_barrier();
                asm volatile("" ::: "memory");
            }
        }
    }
}

// ---------------------------------------------------------------------------
// Fused q1_mean + stage1 + stage2. One wave per (b,t). x out in bf16.
// qbf rows are NATURAL (b,c,t) order: row (b*6+c)*512 + t.
__global__ __launch_bounds__(64) void fused_attn(const ushort* __restrict__ qbf,
                                                 const float* __restrict__ kproj,
                                                 const float* __restrict__ vproj,
                                                 const int* __restrict__ mask,
                                                 ushort* __restrict__ xout) {
    int bt = blockIdx.x;
    int b = bt >> 9, t = bt & 511;
    int lane = threadIdx.x;

    __shared__ ushort qlds[6 * 512];
    __shared__ float q1l[512];
    __shared__ float pcl[512];
    __shared__ float ssl[48];
    __shared__ float a2l[48];

#pragma unroll
    for (int i = 0; i < 6; ++i) {
        long base = ((long)(b * 6 + i) * 512 + t) * 512;
        *(uint4*)&qlds[i * 512 + lane * 8] = *(const uint4*)(qbf + base + lane * 8);
    }
    __syncthreads();

    {
        float s[8] = {};
#pragma unroll
        for (int c = 0; c < 6; ++c) {
            const ushort* qr = &qlds[c * 512 + lane * 8];
#pragma unroll
            for (int j = 0; j < 8; ++j) s[j] += bfu2f(qr[j]);
        }
#pragma unroll
        for (int j = 0; j < 8; ++j) q1l[lane * 8 + j] = s[j] * (1.0f / 6.0f);
    }
    __syncthreads();

    int h = lane >> 3, s = lane & 7;
    const float* krow = kproj + (long)(b * S_ + s) * 512 + h * 64;
    float sc = 0.f;
#pragma unroll
    for (int d = 0; d < 64; d += 4) {
        float4 kv = *(const float4*)(krow + d);
        sc += q1l[h * 64 + d]     * kv.x;
        sc += q1l[h * 64 + d + 1] * kv.y;
        sc += q1l[h * 64 + d + 2] * kv.z;
        sc += q1l[h * 64 + d + 3] * kv.w;
    }
    sc *= 0.125f;
    int mk = mask[((long)b * T_ + t) * S_ + s];
    if (mk == 0) sc = -1e30f;
    float mx = sc;
    for (int off = 1; off < 8; off <<= 1) mx = fmaxf(mx, __shfl_xor(mx, off));
    float e = __expf(sc - mx);
    float sum = e;
    for (int off = 1; off < 8; off <<= 1) sum += __shfl_xor(sum, off);
    float attn = e / sum;
    if (mk == 0) attn = 0.f;

#pragma unroll
    for (int i = 0; i < 8; ++i) {
        float acc = 0.f;
#pragma unroll
        for (int s2 = 0; s2 < 8; ++s2) {
            float a = __shfl(attn, i * 8 + s2);
            acc += a * vproj[(long)(b * S_ + s2) * 512 + i * 64 + lane];
        }
        pcl[i * 64 + lane] = acc;
    }
    __syncthreads();

    if (lane < 48) {
        int hh = lane / 6, cc = lane % 6;
        const float* pr = &pcl[hh * 64];
        const ushort* qr = &qlds[cc * 512 + hh * 64];
        float acc = 0.f;
#pragma unroll 8
        for (int d = 0; d < 64; ++d) acc += pr[d] * bfu2f(qr[d]);
        ssl[lane] = acc * 0.125f;
    }
    __syncthreads();
    if (lane < 8) {
        float mx2 = -1e30f;
#pragma unroll
        for (int c = 0; c < 6; ++c) mx2 = fmaxf(mx2, ssl[lane * 6 + c]);
        float ex[6];
        float sm = 0.f;
#pragma unroll
        for (int c = 0; c < 6; ++c) {
            ex[c] = __expf(ssl[lane * 6 + c] - mx2);
            sm += ex[c];
        }
        float inv = 1.0f / sm;
#pragma unroll
        for (int c = 0; c < 6; ++c) a2l[lane * 6 + c] = ex[c] * inv;
    }
    __syncthreads();

#pragma unroll
    for (int i = 0; i < 8; ++i) {
        float acc = 0.f;
#pragma unroll
        for (int c = 0; c < 6; ++c)
            acc += a2l[i * 6 + c] * bfu2f(qlds[c * 512 + i * 64 + lane]);
        xout[(long)bt * 512 + i * 64 + lane] = f2bf(acc);
    }
}

// ---------------------------------------------------------------------------
extern "C" void kernel_launch(void* const* d_in, const int* in_sizes, int n_in,
                              void* d_out, int out_size, void* d_ws, size_t ws_size,
                              hipStream_t stream) {
    const float* query = (const float*)d_in[0];
    const float* key   = (const float*)d_in[1];
    const float* value = (const float*)d_in[2];
    const int*   mask  = (const int*)d_in[3];
    const float* Wq = (const float*)d_in[4];
    const float* bq = (const float*)d_in[5];
    const float* Wk = (const float*)d_in[6];
    const float* bk = (const float*)d_in[7];
    const float* Wv = (const float*)d_in[8];
    const float* bv = (const float*)d_in[9];
    const float* Wo = (const float*)d_in[10];
    const float* bo = (const float*)d_in[11];
    float* out = (float*)d_out;

    char* ws = (char*)d_ws;
    ushort* Wqbf  = (ushort*)(ws + 0);                  // 512 KB
    ushort* Wobf  = (ushort*)(ws + 524288u);            // 512 KB
    float*  WkT   = (float*)(ws + (1u << 20));          // 1 MB
    float*  WvT   = (float*)(ws + (2u << 20));          // 1 MB
    float*  kproj = (float*)(ws + (3u << 20));          // 256 KB
    float*  vproj = (float*)(ws + (3u << 20) + 262144u);
    ushort* qbf   = (ushort*)(ws + (4u << 20));         // 48 MB, rows (b,c,t)
    ushort* xbf   = (ushort*)(ws + 54525952u);          // 8 MB (8192 x 512 bf16)

    convert2<<<dim3(256, 2), 256, 0, stream>>>(Wq, Wo, Wqbf, Wobf);
    transpose2<<<dim3(16, 16, 2), dim3(32, 8), 0, stream>>>(Wk, Wv, WkT, WvT);

    kv_proj<<<B_ * S_, 512, 0, stream>>>(key, value, WkT, WvT, bk, bv, kproj, vproj);

    // Q projection: M = 49152 rows NATURAL (b,c,t) order, fp32 A, bf16 out
    gemm_mfma<0, 1><<<1536, 256, 0, stream>>>(query, Wqbf, bq, qbf, 384);

    // fused q1_mean + stage1 + stage2 -> x (bf16)
    fused_attn<<<B_ * T_, 64, 0, stream>>>(qbf, kproj, vproj, mask, xbf);

    // output projection: M = 8192, bf16 A (gload_lds both operands), fp32 out
    gemm_mfma<1, 0><<<256, 256, 0, stream>>>(xbf, Wobf, bo, out, 64);

    (void)in_sizes; (void)n_in; (void)out_size; (void)ws_size;
}

// Round 8
// 131.133 us; speedup vs baseline: 1.0480x; 1.0480x over previous
//
#include <hip/hip_runtime.h>
#include <hip/hip_bf16.h>

// Problem constants
#define B_  16
#define C_  6
#define T_  512
#define S_  8

#define AS1 __attribute__((address_space(1)))
#define AS3 __attribute__((address_space(3)))

typedef __attribute__((ext_vector_type(8))) short bf16x8;
typedef __attribute__((ext_vector_type(4))) float f32x4;

__device__ __forceinline__ ushort f2bf(float f) {
    __hip_bfloat16 h = __float2bfloat16(f);
    return *reinterpret_cast<ushort*>(&h);
}
__device__ __forceinline__ float bfu2f(ushort u) {
    uint x = (uint)u << 16;
    union { uint u; float f; } c; c.u = x; return c.f;
}

// ---------------------------------------------------------------------------
// Two 512x512 transposes in one launch (Wk->WkT, Wv->WvT)
__global__ void transpose2(const float* __restrict__ s0, const float* __restrict__ s1,
                           float* __restrict__ d0, float* __restrict__ d1) {
    const float* src = blockIdx.z ? s1 : s0;
    float* dst = blockIdx.z ? d1 : d0;
    __shared__ float tile[32][33];
    int bx = blockIdx.x * 32, by = blockIdx.y * 32;
    int tx = threadIdx.x, ty = threadIdx.y;
    for (int i = 0; i < 32; i += 8)
        tile[ty + i][tx] = src[(long)(by + ty + i) * 512 + bx + tx];
    __syncthreads();
    for (int i = 0; i < 32; i += 8)
        dst[(long)(bx + ty + i) * 512 + by + tx] = tile[tx][ty + i];
}

// Two fp32->bf16 512x512 conversions in one launch (Wq, Wo)
__global__ void convert2(const float* __restrict__ s0, const float* __restrict__ s1,
                         ushort* __restrict__ d0, ushort* __restrict__ d1) {
    const float* s = blockIdx.y ? s1 : s0;
    ushort* d = blockIdx.y ? d1 : d0;
    int i = (blockIdx.x * 256 + threadIdx.x) * 4;
    float4 v = *(const float4*)(s + i);
    ushort4 o;
    o.x = f2bf(v.x); o.y = f2bf(v.y); o.z = f2bf(v.z); o.w = f2bf(v.w);
    *(ushort4*)(d + i) = o;
}

// ---------------------------------------------------------------------------
// K/V projections (tiny: 128 rows)
__global__ void kv_proj(const float* __restrict__ key, const float* __restrict__ value,
                        const float* __restrict__ WkT, const float* __restrict__ WvT,
                        const float* __restrict__ bk, const float* __restrict__ bv,
                        float* __restrict__ kout, float* __restrict__ vout) {
    int row = blockIdx.x;      // b*S + s
    int j = threadIdx.x;       // 0..511
    __shared__ float krow[512];
    __shared__ float vrow[512];
    krow[j] = key[(long)row * 512 + j];
    vrow[j] = value[(long)row * 512 + j];
    __syncthreads();
    float ak = bk[j], av = bv[j];
#pragma unroll 8
    for (int f = 0; f < 512; ++f) {
        ak += krow[f] * WkT[(long)f * 512 + j];
        av += vrow[f] * WvT[(long)f * 512 + j];
    }
    kout[(long)row * 512 + j] = ak;
    vout[(long)row * 512 + j] = av;
}

// ---------------------------------------------------------------------------
// MFMA bf16 GEMM. 128x128 tile, BK=64, 4 waves (2x2), 64x64/wave.
// !ABF16 (fp32 A): A reg-staged with PREFETCH DISTANCE 2 (ra[2], kt-loop fully
//   unrolled -> static reg indexing), W LDS double-buffered via global_load_lds
//   issued at top. Bottom-of-step COUNTED vmcnt(8): drains only W(kt+1)'s 4
//   ops, leaves A(kt+2)'s 8 loads in flight across the barrier -> A(kt+1)
//   gets a full K-step to cover HBM latency. LDS 48 KB.
//   __launch_bounds__(256,2): 256-reg unified budget. (256,3) in R7 capped at
//   ~170 and SPILLED the ra buffers -> 43 MB of scratch writes/dispatch; the
//   spill, not the schedule, was the regression.
//  ABF16: both operands via global_load_lds, double-buffered, distance 1,
//   single barrier per step. LDS 64 KB.
// out[m,n] = sum_k A[m,k]*W[n,k] + bias[n]; N=K=512. grid = mpanels*4 (%8==0).
template <int ABF16, int OUTBF>
__global__ __launch_bounds__(256, 2)
void gemm_mfma(const void* __restrict__ Ain,
               const ushort* __restrict__ Wbf,
               const float* __restrict__ bias,
               void* __restrict__ out, int mpanels) {
    __shared__ __align__(16) ushort lds[ABF16 ? 32768 : 24576];

    const int bid = blockIdx.x;
    const int cpx = (mpanels * 4) >> 3;
    const int swz = (bid & 7) * cpx + (bid >> 3);   // XCD-bijective (grid%8==0)
    const int bm = (swz >> 2) * 128;
    const int bn = (swz & 3) * 128;

    const int tid  = threadIdx.x;
    const int lane = tid & 63;
    const int wv   = tid >> 6;
    const int wm   = (wv >> 1) * 64;
    const int wn   = (wv & 1) * 64;
    const int ln15 = lane & 15;
    const int ln16 = lane >> 4;

    // fp32-A staging slots: thread -> (rows r0+32i, 8-elem k-chunk kc)
    const int kc = tid & 7;
    const int r0 = tid >> 3;

    float4 ra[2][4][2];   // distance-2 reg staging (static indices after unroll)

    auto LOADA = [&](float4 (&r)[4][2], int k0) {
#pragma unroll
        for (int i = 0; i < 4; ++i) {
            const float* ap = (const float*)Ain + (long)(bm + r0 + 32 * i) * 512 + k0 + kc * 8;
            r[i][0] = *(const float4*)ap;
            r[i][1] = *(const float4*)(ap + 4);
        }
    };
    auto WRITEA = [&](float4 (&r)[4][2], ushort* Adst) {
#pragma unroll
        for (int i = 0; i < 4; ++i) {
            int rr = r0 + 32 * i;
            int idx = rr * 64 + ((kc ^ (rr & 7)) << 3);
            uint4 pk;
            pk.x = (uint)f2bf(r[i][0].x) | ((uint)f2bf(r[i][0].y) << 16);
            pk.y = (uint)f2bf(r[i][0].z) | ((uint)f2bf(r[i][0].w) << 16);
            pk.z = (uint)f2bf(r[i][1].x) | ((uint)f2bf(r[i][1].y) << 16);
            pk.w = (uint)f2bf(r[i][1].z) | ((uint)f2bf(r[i][1].w) << 16);
            *(uint4*)&Adst[idx] = pk;
        }
    };
    // global_load_lds stage of a 128x64 bf16 tile (wave wv -> rows wv*32..+31).
    // Linear LDS dest; source pre-swizzled so swizzled reads see W[row][k0+ch*8].
    auto GLDS = [&](const ushort* gbase, int rowbase, ushort* ldsbase, int k0) {
        int rb = wv * 32 + (lane >> 3);
        int c  = lane & 7;
#pragma unroll
        for (int i = 0; i < 4; ++i) {
            int r = rb + i * 8;
            const ushort* src = gbase + (long)(rowbase + r) * 512 + k0 + ((c ^ (r & 7)) << 3);
            ushort* dst = ldsbase + wv * 2048 + i * 512;   // wave-uniform base
            __builtin_amdgcn_global_load_lds((AS1 const void*)src, (AS3 void*)dst, 16, 0, 0);
        }
    };

    // LDS layout
    ushort* asb0 = lds;                                   // A buf 0
    ushort* asb1 = ABF16 ? (lds + 8192) : lds;            // A buf 1 (ABF16 only)
    ushort* wsb[2] = { ABF16 ? (lds + 16384) : (lds + 8192),
                       ABF16 ? (lds + 24576) : (lds + 16384) };

    f32x4 acc[4][4] = {};

    auto MFMA_PHASE = [&](ushort* Asb, ushort* Wsb) {
        __builtin_amdgcn_s_setprio(1);
#pragma unroll
        for (int kj = 0; kj < 2; ++kj) {
            bf16x8 af[4], bfv[4];
#pragma unroll
            for (int mi = 0; mi < 4; ++mi) {
                int row = wm + mi * 16 + ln15;
                int ch  = kj * 4 + ln16;
                af[mi] = *(const bf16x8*)&Asb[row * 64 + ((ch ^ (row & 7)) << 3)];
            }
#pragma unroll
            for (int ni = 0; ni < 4; ++ni) {
                int row = wn + ni * 16 + ln15;
                int ch  = kj * 4 + ln16;
                bfv[ni] = *(const bf16x8*)&Wsb[row * 64 + ((ch ^ (row & 7)) << 3)];
            }
#pragma unroll
            for (int mi = 0; mi < 4; ++mi)
#pragma unroll
                for (int ni = 0; ni < 4; ++ni)
                    acc[mi][ni] = __builtin_amdgcn_mfma_f32_16x16x32_bf16(
                        af[mi], bfv[ni], acc[mi][ni], 0, 0, 0);
        }
        __builtin_amdgcn_s_setprio(0);
    };

    if (ABF16) {
        // ---- simple distance-1 double-buffered pipeline (small kernel) ----
        GLDS((const ushort*)Ain, bm, asb0, 0);
        GLDS(Wbf, bn, wsb[0], 0);
        asm volatile("s_waitcnt vmcnt(0) lgkmcnt(0)" ::: "memory");
        __builtin_amdgcn_sched_barrier(0);
        __builtin_amdgcn_s_barrier();
        asm volatile("" ::: "memory");
#pragma unroll
        for (int kt = 0; kt < 8; ++kt) {
            ushort* Asb = (kt & 1) ? asb1 : asb0;
            ushort* nAs = (kt & 1) ? asb0 : asb1;
            if (kt < 7) {
                GLDS(Wbf, bn, wsb[(kt + 1) & 1], (kt + 1) * 64);
                GLDS((const ushort*)Ain, bm, nAs, (kt + 1) * 64);
            }
            __builtin_amdgcn_sched_barrier(0);
            MFMA_PHASE(Asb, wsb[kt & 1]);
            asm volatile("s_waitcnt vmcnt(0) lgkmcnt(0)" ::: "memory");
            __builtin_amdgcn_sched_barrier(0);
            __builtin_amdgcn_s_barrier();
            asm volatile("" ::: "memory");
        }
    } else {
        // ---- distance-2 counted pipeline ----
        // prologue: ra[0]<-tile0, W0 staged, ra[1]<-tile1 (stays in flight)
        LOADA(ra[0], 0);
        GLDS(Wbf, bn, wsb[0], 0);
        LOADA(ra[1], 64);
        WRITEA(ra[0], asb0);                       // compiler waits ra[0] only
        asm volatile("s_waitcnt vmcnt(8) lgkmcnt(0)" ::: "memory");  // W0 done; ra[1] flies
        __builtin_amdgcn_sched_barrier(0);
        __builtin_amdgcn_s_barrier();
        asm volatile("" ::: "memory");

#pragma unroll
        for (int kt = 0; kt < 8; ++kt) {
            // top: stage W(kt+1) FIRST (so counted vmcnt can drain it without
            // draining A), then A(kt+2) -> ra[kt&1] (now free)
            if (kt < 7) GLDS(Wbf, bn, wsb[(kt + 1) & 1], (kt + 1) * 64);
            if (kt + 2 < 8) LOADA(ra[kt & 1], (kt + 2) * 64);
            __builtin_amdgcn_sched_barrier(0);

            MFMA_PHASE(asb0, wsb[kt & 1]);

            // bar1: all waves done reading asb0
            asm volatile("" ::: "memory");
            __builtin_amdgcn_s_barrier();
            asm volatile("" ::: "memory");

            if (kt < 7) WRITEA(ra[(kt + 1) & 1], asb0);   // tile kt+1 (loaded @ kt-1)

            // counted wait: drain W(kt+1) (4 ops), keep A(kt+2) (8 ops) in flight
            if (kt < 6) {
                asm volatile("s_waitcnt vmcnt(8) lgkmcnt(0)" ::: "memory");
            } else {
                asm volatile("s_waitcnt vmcnt(0) lgkmcnt(0)" ::: "memory");
            }
            __builtin_amdgcn_sched_barrier(0);
            __builtin_amdgcn_s_barrier();
            asm volatile("" ::: "memory");
        }
    }

    // ---- epilogue ----
    float bsv[4];
#pragma unroll
    for (int ni = 0; ni < 4; ++ni)
        bsv[ni] = bias[bn + wn + ni * 16 + ln15];

    if (OUTBF) {
        ushort* eb = lds;    // 128x128 bf16 = 32 KB
#pragma unroll
        for (int mi = 0; mi < 4; ++mi)
#pragma unroll
            for (int j = 0; j < 4; ++j) {
                int row = wm + mi * 16 + ln16 * 4 + j;
#pragma unroll
                for (int ni = 0; ni < 4; ++ni) {
                    int col = wn + ni * 16 + ln15;
                    int cs  = col ^ ((row & 12) << 2);
                    eb[row * 128 + cs] = f2bf(acc[mi][ni][j] + bsv[ni]);
                }
            }
        asm volatile("s_waitcnt lgkmcnt(0)" ::: "memory");
        __builtin_amdgcn_sched_barrier(0);
        __builtin_amdgcn_s_barrier();
        asm volatile("" ::: "memory");
#pragma unroll
        for (int i = 0; i < 8; ++i) {
            int idx = i * 2048 + tid * 8;
            int row = idx >> 7, col = idx & 127;
            int cs  = col ^ ((row & 12) << 2);
            uint4 v = *(const uint4*)&eb[row * 128 + cs];
            *(uint4*)((ushort*)out + (long)(bm + row) * 512 + bn + col) = v;
        }
    } else {
        // fp32 out: stage in two 64-row halves (32 KB each)
        float* ef = (float*)lds;
#pragma unroll
        for (int half = 0; half < 2; ++half) {
            if (wm == half * 64) {
#pragma unroll
                for (int mi = 0; mi < 4; ++mi)
#pragma unroll
                    for (int j = 0; j < 4; ++j) {
                        int lr = mi * 16 + ln16 * 4 + j;
#pragma unroll
                        for (int ni = 0; ni < 4; ++ni) {
                            int col = wn + ni * 16 + ln15;
                            int cs  = col ^ ((lr & 12) << 2);
                            ef[lr * 128 + cs] = acc[mi][ni][j] + bsv[ni];
                        }
                    }
            }
            asm volatile("s_waitcnt lgkmcnt(0)" ::: "memory");
            __builtin_amdgcn_sched_barrier(0);
            __builtin_amdgcn_s_barrier();
            asm volatile("" ::: "memory");
#pragma unroll
            for (int i = 0; i < 8; ++i) {
                int idx = i * 1024 + tid * 4;
                int lr = idx >> 7, col = idx & 127;
                int cs = col ^ ((lr & 12) << 2);
                float4 v = *(const float4*)&ef[lr * 128 + cs];
                *(float4*)((float*)out + (long)(bm + half * 64 + lr) * 512 + bn + col) = v;
            }
            if (half == 0) {
                asm volatile("" ::: "memory");
                __builtin_amdgcn_s_barrier();
                asm volatile("" ::: "memory");
            }
        }
    }
}

// ---------------------------------------------------------------------------
// Fused q1_mean + stage1 + stage2. One wave per (b,t). x out in bf16.
// qbf rows are NATURAL (b,c,t) order: row (b*6+c)*512 + t.
__global__ __launch_bounds__(64) void fused_attn(const ushort* __restrict__ qbf,
                                                 const float* __restrict__ kproj,
                                                 const float* __restrict__ vproj,
                                                 const int* __restrict__ mask,
                                                 ushort* __restrict__ xout) {
    int bt = blockIdx.x;
    int b = bt >> 9, t = bt & 511;
    int lane = threadIdx.x;

    __shared__ ushort qlds[6 * 512];
    __shared__ float q1l[512];
    __shared__ float pcl[512];
    __shared__ float ssl[48];
    __shared__ float a2l[48];

#pragma unroll
    for (int i = 0; i < 6; ++i) {
        long base = ((long)(b * 6 + i) * 512 + t) * 512;
        *(uint4*)&qlds[i * 512 + lane * 8] = *(const uint4*)(qbf + base + lane * 8);
    }
    __syncthreads();

    {
        float s[8] = {};
#pragma unroll
        for (int c = 0; c < 6; ++c) {
            const ushort* qr = &qlds[c * 512 + lane * 8];
#pragma unroll
            for (int j = 0; j < 8; ++j) s[j] += bfu2f(qr[j]);
        }
#pragma unroll
        for (int j = 0; j < 8; ++j) q1l[lane * 8 + j] = s[j] * (1.0f / 6.0f);
    }
    __syncthreads();

    int h = lane >> 3, s = lane & 7;
    const float* krow = kproj + (long)(b * S_ + s) * 512 + h * 64;
    float sc = 0.f;
#pragma unroll
    for (int d = 0; d < 64; d += 4) {
        float4 kv = *(const float4*)(krow + d);
        sc += q1l[h * 64 + d]     * kv.x;
        sc += q1l[h * 64 + d + 1] * kv.y;
        sc += q1l[h * 64 + d + 2] * kv.z;
        sc += q1l[h * 64 + d + 3] * kv.w;
    }
    sc *= 0.125f;
    int mk = mask[((long)b * T_ + t) * S_ + s];
    if (mk == 0) sc = -1e30f;
    float mx = sc;
    for (int off = 1; off < 8; off <<= 1) mx = fmaxf(mx, __shfl_xor(mx, off));
    float e = __expf(sc - mx);
    float sum = e;
    for (int off = 1; off < 8; off <<= 1) sum += __shfl_xor(sum, off);
    float attn = e / sum;
    if (mk == 0) attn = 0.f;

#pragma unroll
    for (int i = 0; i < 8; ++i) {
        float acc = 0.f;
#pragma unroll
        for (int s2 = 0; s2 < 8; ++s2) {
            float a = __shfl(attn, i * 8 + s2);
            acc += a * vproj[(long)(b * S_ + s2) * 512 + i * 64 + lane];
        }
        pcl[i * 64 + lane] = acc;
    }
    __syncthreads();

    if (lane < 48) {
        int hh = lane / 6, cc = lane % 6;
        const float* pr = &pcl[hh * 64];
        const ushort* qr = &qlds[cc * 512 + hh * 64];
        float acc = 0.f;
#pragma unroll 8
        for (int d = 0; d < 64; ++d) acc += pr[d] * bfu2f(qr[d]);
        ssl[lane] = acc * 0.125f;
    }
    __syncthreads();
    if (lane < 8) {
        float mx2 = -1e30f;
#pragma unroll
        for (int c = 0; c < 6; ++c) mx2 = fmaxf(mx2, ssl[lane * 6 + c]);
        float ex[6];
        float sm = 0.f;
#pragma unroll
        for (int c = 0; c < 6; ++c) {
            ex[c] = __expf(ssl[lane * 6 + c] - mx2);
            sm += ex[c];
        }
        float inv = 1.0f / sm;
#pragma unroll
        for (int c = 0; c < 6; ++c) a2l[lane * 6 + c] = ex[c] * inv;
    }
    __syncthreads();

#pragma unroll
    for (int i = 0; i < 8; ++i) {
        float acc = 0.f;
#pragma unroll
        for (int c = 0; c < 6; ++c)
            acc += a2l[i * 6 + c] * bfu2f(qlds[c * 512 + i * 64 + lane]);
        xout[(long)bt * 512 + i * 64 + lane] = f2bf(acc);
    }
}

// ---------------------------------------------------------------------------
extern "C" void kernel_launch(void* const* d_in, const int* in_sizes, int n_in,
                              void* d_out, int out_size, void* d_ws, size_t ws_size,
                              hipStream_t stream) {
    const float* query = (const float*)d_in[0];
    const float* key   = (const float*)d_in[1];
    const float* value = (const float*)d_in[2];
    const int*   mask  = (const int*)d_in[3];
    const float* Wq = (const float*)d_in[4];
    const float* bq = (const float*)d_in[5];
    const float* Wk = (const float*)d_in[6];
    const float* bk = (const float*)d_in[7];
    const float* Wv = (const float*)d_in[8];
    const float* bv = (const float*)d_in[9];
    const float* Wo = (const float*)d_in[10];
    const float* bo = (const float*)d_in[11];
    float* out = (float*)d_out;

    char* ws = (char*)d_ws;
    ushort* Wqbf  = (ushort*)(ws + 0);                  // 512 KB
    ushort* Wobf  = (ushort*)(ws + 524288u);            // 512 KB
    float*  WkT   = (float*)(ws + (1u << 20));          // 1 MB
    float*  WvT   = (float*)(ws + (2u << 20));          // 1 MB
    float*  kproj = (float*)(ws + (3u << 20));          // 256 KB
    float*  vproj = (float*)(ws + (3u << 20) + 262144u);
    ushort* qbf   = (ushort*)(ws + (4u << 20));         // 48 MB, rows (b,c,t)
    ushort* xbf   = (ushort*)(ws + 54525952u);          // 8 MB (8192 x 512 bf16)

    convert2<<<dim3(256, 2), 256, 0, stream>>>(Wq, Wo, Wqbf, Wobf);
    transpose2<<<dim3(16, 16, 2), dim3(32, 8), 0, stream>>>(Wk, Wv, WkT, WvT);

    kv_proj<<<B_ * S_, 512, 0, stream>>>(key, value, WkT, WvT, bk, bv, kproj, vproj);

    // Q projection: M = 49152 rows NATURAL (b,c,t) order, fp32 A, bf16 out
    gemm_mfma<0, 1><<<1536, 256, 0, stream>>>(query, Wqbf, bq, qbf, 384);

    // fused q1_mean + stage1 + stage2 -> x (bf16)
    fused_attn<<<B_ * T_, 64, 0, stream>>>(qbf, kproj, vproj, mask, xbf);

    // output projection: M = 8192, bf16 A (gload_lds both operands), fp32 out
    gemm_mfma<1, 0><<<256, 256, 0, stream>>>(xbf, Wobf, bo, out, 64);

    (void)in_sizes; (void)n_in; (void)out_size; (void)ws_size;
}

// Round 9
// 121.310 us; speedup vs baseline: 1.1329x; 1.0810x over previous
//
#include <hip/hip_runtime.h>
#include <hip/hip_bf16.h>

// Problem constants
#define B_  16
#define C_  6
#define T_  512
#define S_  8

#define AS1 __attribute__((address_space(1)))
#define AS3 __attribute__((address_space(3)))

typedef __attribute__((ext_vector_type(8))) short bf16x8;
typedef __attribute__((ext_vector_type(4))) float f32x4;

__device__ __forceinline__ ushort f2bf(float f) {
    __hip_bfloat16 h = __float2bfloat16(f);
    return *reinterpret_cast<ushort*>(&h);
}
__device__ __forceinline__ float bfu2f(ushort u) {
    uint x = (uint)u << 16;
    union { uint u; float f; } c; c.u = x; return c.f;
}

// ---------------------------------------------------------------------------
// Two 512x512 transposes in one launch (Wk->WkT, Wv->WvT)
__global__ void transpose2(const float* __restrict__ s0, const float* __restrict__ s1,
                           float* __restrict__ d0, float* __restrict__ d1) {
    const float* src = blockIdx.z ? s1 : s0;
    float* dst = blockIdx.z ? d1 : d0;
    __shared__ float tile[32][33];
    int bx = blockIdx.x * 32, by = blockIdx.y * 32;
    int tx = threadIdx.x, ty = threadIdx.y;
    for (int i = 0; i < 32; i += 8)
        tile[ty + i][tx] = src[(long)(by + ty + i) * 512 + bx + tx];
    __syncthreads();
    for (int i = 0; i < 32; i += 8)
        dst[(long)(bx + ty + i) * 512 + by + tx] = tile[tx][ty + i];
}

// Two fp32->bf16 512x512 conversions in one launch (Wq, Wo)
__global__ void convert2(const float* __restrict__ s0, const float* __restrict__ s1,
                         ushort* __restrict__ d0, ushort* __restrict__ d1) {
    const float* s = blockIdx.y ? s1 : s0;
    ushort* d = blockIdx.y ? d1 : d0;
    int i = (blockIdx.x * 256 + threadIdx.x) * 4;
    float4 v = *(const float4*)(s + i);
    ushort4 o;
    o.x = f2bf(v.x); o.y = f2bf(v.y); o.z = f2bf(v.z); o.w = f2bf(v.w);
    *(ushort4*)(d + i) = o;
}

// ---------------------------------------------------------------------------
// K/V projections (tiny: 128 rows)
__global__ void kv_proj(const float* __restrict__ key, const float* __restrict__ value,
                        const float* __restrict__ WkT, const float* __restrict__ WvT,
                        const float* __restrict__ bk, const float* __restrict__ bv,
                        float* __restrict__ kout, float* __restrict__ vout) {
    int row = blockIdx.x;      // b*S + s
    int j = threadIdx.x;       // 0..511
    __shared__ float krow[512];
    __shared__ float vrow[512];
    krow[j] = key[(long)row * 512 + j];
    vrow[j] = value[(long)row * 512 + j];
    __syncthreads();
    float ak = bk[j], av = bv[j];
#pragma unroll 8
    for (int f = 0; f < 512; ++f) {
        ak += krow[f] * WkT[(long)f * 512 + j];
        av += vrow[f] * WvT[(long)f * 512 + j];
    }
    kout[(long)row * 512 + j] = ak;
    vout[(long)row * 512 + j] = av;
}

// ---------------------------------------------------------------------------
// MFMA bf16 GEMM. 128x128 tile, BK=64, 4 waves (2x2), 64x64/wave.
// !ABF16 (fp32 A), per step kt:
//   (1) WRITEA(A(kt))  <- loads in flight since step kt-1: FULL-STEP cover
//   (2) GLDS W(kt+1) -> wsb^1 ; LOADA A(kt+1) -> ra   (order pinned)
//   (3) lgkmcnt(0); barrier
//   (4) MFMA(asb, wsb[kt&1])
//   (5) s_waitcnt vmcnt(8): drain W(kt+1) ONLY (4 oldest), keep A(kt+1)'s
//       8 loads in flight across the barrier (T4: never drain A mid-loop)
// A single-buffered LDS 16 KB, W double-buffered 32 KB -> 48 KB, 3 blk/CU,
// distance-1 regs (ra 32 VGPR) -> no spill at the (256,3) cap (R6-proven).
//  ABF16: both operands via global_load_lds, dbuf, single barrier per step.
// out[m,n] = sum_k A[m,k]*W[n,k] + bias[n]; N=K=512. grid = mpanels*4 (%8==0).
template <int ABF16, int OUTBF>
__global__ __launch_bounds__(256, ABF16 ? 2 : 3)
void gemm_mfma(const void* __restrict__ Ain,
               const ushort* __restrict__ Wbf,
               const float* __restrict__ bias,
               void* __restrict__ out, int mpanels) {
    __shared__ __align__(16) ushort lds[ABF16 ? 32768 : 24576];

    const int bid = blockIdx.x;
    const int cpx = (mpanels * 4) >> 3;
    const int swz = (bid & 7) * cpx + (bid >> 3);   // XCD-bijective (grid%8==0)
    const int bm = (swz >> 2) * 128;
    const int bn = (swz & 3) * 128;

    const int tid  = threadIdx.x;
    const int lane = tid & 63;
    const int wv   = tid >> 6;
    const int wm   = (wv >> 1) * 64;
    const int wn   = (wv & 1) * 64;
    const int ln15 = lane & 15;
    const int ln16 = lane >> 4;

    // fp32-A staging slots: thread -> (rows r0+32i, 8-elem k-chunk kc)
    const int kc = tid & 7;
    const int r0 = tid >> 3;

    float4 ra[4][2];   // distance-1 reg staging

    auto LOADA = [&](int k0) {
#pragma unroll
        for (int i = 0; i < 4; ++i) {
            const float* ap = (const float*)Ain + (long)(bm + r0 + 32 * i) * 512 + k0 + kc * 8;
            ra[i][0] = *(const float4*)ap;
            ra[i][1] = *(const float4*)(ap + 4);
        }
    };
    auto WRITEA = [&](ushort* Adst) {
#pragma unroll
        for (int i = 0; i < 4; ++i) {
            int rr = r0 + 32 * i;
            int idx = rr * 64 + ((kc ^ (rr & 7)) << 3);
            uint4 pk;
            pk.x = (uint)f2bf(ra[i][0].x) | ((uint)f2bf(ra[i][0].y) << 16);
            pk.y = (uint)f2bf(ra[i][0].z) | ((uint)f2bf(ra[i][0].w) << 16);
            pk.z = (uint)f2bf(ra[i][1].x) | ((uint)f2bf(ra[i][1].y) << 16);
            pk.w = (uint)f2bf(ra[i][1].z) | ((uint)f2bf(ra[i][1].w) << 16);
            *(uint4*)&Adst[idx] = pk;
        }
    };
    // global_load_lds stage of a 128x64 bf16 tile (wave wv -> rows wv*32..+31).
    // Linear LDS dest; source pre-swizzled so swizzled reads see W[row][k0+ch*8].
    auto GLDS = [&](const ushort* gbase, int rowbase, ushort* ldsbase, int k0) {
        int rb = wv * 32 + (lane >> 3);
        int c  = lane & 7;
#pragma unroll
        for (int i = 0; i < 4; ++i) {
            int r = rb + i * 8;
            const ushort* src = gbase + (long)(rowbase + r) * 512 + k0 + ((c ^ (r & 7)) << 3);
            ushort* dst = ldsbase + wv * 2048 + i * 512;   // wave-uniform base
            __builtin_amdgcn_global_load_lds((AS1 const void*)src, (AS3 void*)dst, 16, 0, 0);
        }
    };

    // LDS layout
    ushort* asb0 = lds;                                   // A buf 0
    ushort* asb1 = ABF16 ? (lds + 8192) : lds;            // A buf 1 (ABF16 only)
    ushort* wsb[2] = { ABF16 ? (lds + 16384) : (lds + 8192),
                       ABF16 ? (lds + 24576) : (lds + 16384) };

    f32x4 acc[4][4] = {};

    auto MFMA_PHASE = [&](ushort* Asb, ushort* Wsb) {
        __builtin_amdgcn_s_setprio(1);
#pragma unroll
        for (int kj = 0; kj < 2; ++kj) {
            bf16x8 af[4], bfv[4];
#pragma unroll
            for (int mi = 0; mi < 4; ++mi) {
                int row = wm + mi * 16 + ln15;
                int ch  = kj * 4 + ln16;
                af[mi] = *(const bf16x8*)&Asb[row * 64 + ((ch ^ (row & 7)) << 3)];
            }
#pragma unroll
            for (int ni = 0; ni < 4; ++ni) {
                int row = wn + ni * 16 + ln15;
                int ch  = kj * 4 + ln16;
                bfv[ni] = *(const bf16x8*)&Wsb[row * 64 + ((ch ^ (row & 7)) << 3)];
            }
#pragma unroll
            for (int mi = 0; mi < 4; ++mi)
#pragma unroll
                for (int ni = 0; ni < 4; ++ni)
                    acc[mi][ni] = __builtin_amdgcn_mfma_f32_16x16x32_bf16(
                        af[mi], bfv[ni], acc[mi][ni], 0, 0, 0);
        }
        __builtin_amdgcn_s_setprio(0);
    };

    if (ABF16) {
        // ---- distance-1 double-buffered pipeline (small kernel) ----
        GLDS((const ushort*)Ain, bm, asb0, 0);
        GLDS(Wbf, bn, wsb[0], 0);
        asm volatile("s_waitcnt vmcnt(0) lgkmcnt(0)" ::: "memory");
        __builtin_amdgcn_sched_barrier(0);
        __builtin_amdgcn_s_barrier();
        asm volatile("" ::: "memory");
#pragma unroll
        for (int kt = 0; kt < 8; ++kt) {
            ushort* Asb = (kt & 1) ? asb1 : asb0;
            ushort* nAs = (kt & 1) ? asb0 : asb1;
            if (kt < 7) {
                GLDS(Wbf, bn, wsb[(kt + 1) & 1], (kt + 1) * 64);
                GLDS((const ushort*)Ain, bm, nAs, (kt + 1) * 64);
            }
            __builtin_amdgcn_sched_barrier(0);
            MFMA_PHASE(Asb, wsb[kt & 1]);
            asm volatile("s_waitcnt vmcnt(0) lgkmcnt(0)" ::: "memory");
            __builtin_amdgcn_sched_barrier(0);
            __builtin_amdgcn_s_barrier();
            asm volatile("" ::: "memory");
        }
    } else {
        // ---- full-step-cover pipeline, distance-1 regs, counted W drain ----
        // prologue: A(0) -> ra, W(0) -> wsb0 (both stay in flight)
        LOADA(0);
        __builtin_amdgcn_sched_barrier(0);
        GLDS(Wbf, bn, wsb[0], 0);
        __builtin_amdgcn_sched_barrier(0);

#pragma unroll
        for (int kt = 0; kt < 8; ++kt) {
            // (1) write A(kt) to LDS — reg-dep drains A(kt) loads (full cover)
            WRITEA(asb0);
            __builtin_amdgcn_sched_barrier(0);
            // (2) issue next tile: W first (so counted vmcnt targets it), then A
            if (kt < 7) {
                GLDS(Wbf, bn, wsb[(kt + 1) & 1], (kt + 1) * 64);
                __builtin_amdgcn_sched_barrier(0);
                LOADA((kt + 1) * 64);
                __builtin_amdgcn_sched_barrier(0);
            }
            // (3) A-tile visible to all waves; step-0 additionally drains W(0)
            if (kt == 0) {
                if (kt < 7) asm volatile("s_waitcnt vmcnt(12) lgkmcnt(0)" ::: "memory");
                else        asm volatile("s_waitcnt vmcnt(0) lgkmcnt(0)" ::: "memory");
            } else {
                asm volatile("s_waitcnt lgkmcnt(0)" ::: "memory");
            }
            __builtin_amdgcn_sched_barrier(0);
            __builtin_amdgcn_s_barrier();
            asm volatile("" ::: "memory");

            // (4) compute
            MFMA_PHASE(asb0, wsb[kt & 1]);

            // (5) drain W(kt+1) only (4 oldest); A(kt+1)'s 8 loads keep flying
            if (kt < 7) {
                asm volatile("s_waitcnt vmcnt(8)" ::: "memory");
            } else {
                asm volatile("s_waitcnt vmcnt(0) lgkmcnt(0)" ::: "memory");
            }
            __builtin_amdgcn_sched_barrier(0);
            __builtin_amdgcn_s_barrier();
            asm volatile("" ::: "memory");
        }
    }

    // ---- epilogue ----
    float bsv[4];
#pragma unroll
    for (int ni = 0; ni < 4; ++ni)
        bsv[ni] = bias[bn + wn + ni * 16 + ln15];

    if (OUTBF) {
        ushort* eb = lds;    // 128x128 bf16 = 32 KB
#pragma unroll
        for (int mi = 0; mi < 4; ++mi)
#pragma unroll
            for (int j = 0; j < 4; ++j) {
                int row = wm + mi * 16 + ln16 * 4 + j;
#pragma unroll
                for (int ni = 0; ni < 4; ++ni) {
                    int col = wn + ni * 16 + ln15;
                    int cs  = col ^ ((row & 12) << 2);
                    eb[row * 128 + cs] = f2bf(acc[mi][ni][j] + bsv[ni]);
                }
            }
        asm volatile("s_waitcnt lgkmcnt(0)" ::: "memory");
        __builtin_amdgcn_sched_barrier(0);
        __builtin_amdgcn_s_barrier();
        asm volatile("" ::: "memory");
#pragma unroll
        for (int i = 0; i < 8; ++i) {
            int idx = i * 2048 + tid * 8;
            int row = idx >> 7, col = idx & 127;
            int cs  = col ^ ((row & 12) << 2);
            uint4 v = *(const uint4*)&eb[row * 128 + cs];
            *(uint4*)((ushort*)out + (long)(bm + row) * 512 + bn + col) = v;
        }
    } else {
        // fp32 out: stage in two 64-row halves (32 KB each)
        float* ef = (float*)lds;
#pragma unroll
        for (int half = 0; half < 2; ++half) {
            if (wm == half * 64) {
#pragma unroll
                for (int mi = 0; mi < 4; ++mi)
#pragma unroll
                    for (int j = 0; j < 4; ++j) {
                        int lr = mi * 16 + ln16 * 4 + j;
#pragma unroll
                        for (int ni = 0; ni < 4; ++ni) {
                            int col = wn + ni * 16 + ln15;
                            int cs  = col ^ ((lr & 12) << 2);
                            ef[lr * 128 + cs] = acc[mi][ni][j] + bsv[ni];
                        }
                    }
            }
            asm volatile("s_waitcnt lgkmcnt(0)" ::: "memory");
            __builtin_amdgcn_sched_barrier(0);
            __builtin_amdgcn_s_barrier();
            asm volatile("" ::: "memory");
#pragma unroll
            for (int i = 0; i < 8; ++i) {
                int idx = i * 1024 + tid * 4;
                int lr = idx >> 7, col = idx & 127;
                int cs = col ^ ((lr & 12) << 2);
                float4 v = *(const float4*)&ef[lr * 128 + cs];
                *(float4*)((float*)out + (long)(bm + half * 64 + lr) * 512 + bn + col) = v;
            }
            if (half == 0) {
                asm volatile("" ::: "memory");
                __builtin_amdgcn_s_barrier();
                asm volatile("" ::: "memory");
            }
        }
    }
}

// ---------------------------------------------------------------------------
// Fused q1_mean + stage1 + stage2. One wave per (b,t). x out in bf16.
// qbf rows are NATURAL (b,c,t) order: row (b*6+c)*512 + t.
__global__ __launch_bounds__(64) void fused_attn(const ushort* __restrict__ qbf,
                                                 const float* __restrict__ kproj,
                                                 const float* __restrict__ vproj,
                                                 const int* __restrict__ mask,
                                                 ushort* __restrict__ xout) {
    int bt = blockIdx.x;
    int b = bt >> 9, t = bt & 511;
    int lane = threadIdx.x;

    __shared__ ushort qlds[6 * 512];
    __shared__ float q1l[512];
    __shared__ float pcl[512];
    __shared__ float ssl[48];
    __shared__ float a2l[48];

#pragma unroll
    for (int i = 0; i < 6; ++i) {
        long base = ((long)(b * 6 + i) * 512 + t) * 512;
        *(uint4*)&qlds[i * 512 + lane * 8] = *(const uint4*)(qbf + base + lane * 8);
    }
    __syncthreads();

    {
        float s[8] = {};
#pragma unroll
        for (int c = 0; c < 6; ++c) {
            const ushort* qr = &qlds[c * 512 + lane * 8];
#pragma unroll
            for (int j = 0; j < 8; ++j) s[j] += bfu2f(qr[j]);
        }
#pragma unroll
        for (int j = 0; j < 8; ++j) q1l[lane * 8 + j] = s[j] * (1.0f / 6.0f);
    }
    __syncthreads();

    int h = lane >> 3, s = lane & 7;
    const float* krow = kproj + (long)(b * S_ + s) * 512 + h * 64;
    float sc = 0.f;
#pragma unroll
    for (int d = 0; d < 64; d += 4) {
        float4 kv = *(const float4*)(krow + d);
        sc += q1l[h * 64 + d]     * kv.x;
        sc += q1l[h * 64 + d + 1] * kv.y;
        sc += q1l[h * 64 + d + 2] * kv.z;
        sc += q1l[h * 64 + d + 3] * kv.w;
    }
    sc *= 0.125f;
    int mk = mask[((long)b * T_ + t) * S_ + s];
    if (mk == 0) sc = -1e30f;
    float mx = sc;
    for (int off = 1; off < 8; off <<= 1) mx = fmaxf(mx, __shfl_xor(mx, off));
    float e = __expf(sc - mx);
    float sum = e;
    for (int off = 1; off < 8; off <<= 1) sum += __shfl_xor(sum, off);
    float attn = e / sum;
    if (mk == 0) attn = 0.f;

#pragma unroll
    for (int i = 0; i < 8; ++i) {
        float acc = 0.f;
#pragma unroll
        for (int s2 = 0; s2 < 8; ++s2) {
            float a = __shfl(attn, i * 8 + s2);
            acc += a * vproj[(long)(b * S_ + s2) * 512 + i * 64 + lane];
        }
        pcl[i * 64 + lane] = acc;
    }
    __syncthreads();

    if (lane < 48) {
        int hh = lane / 6, cc = lane % 6;
        const float* pr = &pcl[hh * 64];
        const ushort* qr = &qlds[cc * 512 + hh * 64];
        float acc = 0.f;
#pragma unroll 8
        for (int d = 0; d < 64; ++d) acc += pr[d] * bfu2f(qr[d]);
        ssl[lane] = acc * 0.125f;
    }
    __syncthreads();
    if (lane < 8) {
        float mx2 = -1e30f;
#pragma unroll
        for (int c = 0; c < 6; ++c) mx2 = fmaxf(mx2, ssl[lane * 6 + c]);
        float ex[6];
        float sm = 0.f;
#pragma unroll
        for (int c = 0; c < 6; ++c) {
            ex[c] = __expf(ssl[lane * 6 + c] - mx2);
            sm += ex[c];
        }
        float inv = 1.0f / sm;
#pragma unroll
        for (int c = 0; c < 6; ++c) a2l[lane * 6 + c] = ex[c] * inv;
    }
    __syncthreads();

#pragma unroll
    for (int i = 0; i < 8; ++i) {
        float acc = 0.f;
#pragma unroll
        for (int c = 0; c < 6; ++c)
            acc += a2l[i * 6 + c] * bfu2f(qlds[c * 512 + i * 64 + lane]);
        xout[(long)bt * 512 + i * 64 + lane] = f2bf(acc);
    }
}

// ---------------------------------------------------------------------------
extern "C" void kernel_launch(void* const* d_in, const int* in_sizes, int n_in,
                              void* d_out, int out_size, void* d_ws, size_t ws_size,
                              hipStream_t stream) {
    const float* query = (const float*)d_in[0];
    const float* key   = (const float*)d_in[1];
    const float* value = (const float*)d_in[2];
    const int*   mask  = (const int*)d_in[3];
    const float* Wq = (const float*)d_in[4];
    const float* bq = (const float*)d_in[5];
    const float* Wk = (const float*)d_in[6];
    const float* bk = (const float*)d_in[7];
    const float* Wv = (const float*)d_in[8];
    const float* bv = (const float*)d_in[9];
    const float* Wo = (const float*)d_in[10];
    const float* bo = (const float*)d_in[11];
    float* out = (float*)d_out;

    char* ws = (char*)d_ws;
    ushort* Wqbf  = (ushort*)(ws + 0);                  // 512 KB
    ushort* Wobf  = (ushort*)(ws + 524288u);            // 512 KB
    float*  WkT   = (float*)(ws + (1u << 20));          // 1 MB
    float*  WvT   = (float*)(ws + (2u << 20));          // 1 MB
    float*  kproj = (float*)(ws + (3u << 20));          // 256 KB
    float*  vproj = (float*)(ws + (3u << 20) + 262144u);
    ushort* qbf   = (ushort*)(ws + (4u << 20));         // 48 MB, rows (b,c,t)
    ushort* xbf   = (ushort*)(ws + 54525952u);          // 8 MB (8192 x 512 bf16)

    convert2<<<dim3(256, 2), 256, 0, stream>>>(Wq, Wo, Wqbf, Wobf);
    transpose2<<<dim3(16, 16, 2), dim3(32, 8), 0, stream>>>(Wk, Wv, WkT, WvT);

    kv_proj<<<B_ * S_, 512, 0, stream>>>(key, value, WkT, WvT, bk, bv, kproj, vproj);

    // Q projection: M = 49152 rows NATURAL (b,c,t) order, fp32 A, bf16 out
    gemm_mfma<0, 1><<<1536, 256, 0, stream>>>(query, Wqbf, bq, qbf, 384);

    // fused q1_mean + stage1 + stage2 -> x (bf16)
    fused_attn<<<B_ * T_, 64, 0, stream>>>(qbf, kproj, vproj, mask, xbf);

    // output projection: M = 8192, bf16 A (gload_lds both operands), fp32 out
    gemm_mfma<1, 0><<<256, 256, 0, stream>>>(xbf, Wobf, bo, out, 64);

    (void)in_sizes; (void)n_in; (void)out_size; (void)ws_size;
}